// Round 1
// baseline (298.657 us; speedup 1.0000x reference)
//
#include <hip/hip_runtime.h>

#define NN 10000
#define NE 640000
#define DIM 128

// ---------------- CSR build ----------------
__global__ void hist_k(const int* __restrict__ dst, int* __restrict__ deg, int E) {
    int e = blockIdx.x * blockDim.x + threadIdx.x;
    if (e < E) atomicAdd(&deg[dst[e]], 1);
}

__global__ __launch_bounds__(1024) void scan_k(const int* __restrict__ deg,
        int* __restrict__ rowptr, int* __restrict__ cursor, int N) {
    __shared__ int buf[1024];
    int t = threadIdx.x;
    int chunk = (N + 1023) >> 10;
    int beg = t * chunk;
    int end = min(beg + chunk, N);
    int sum = 0;
    for (int i = beg; i < end; ++i) sum += deg[i];
    buf[t] = sum;
    __syncthreads();
    for (int off = 1; off < 1024; off <<= 1) {
        int v = (t >= off) ? buf[t - off] : 0;
        __syncthreads();
        buf[t] += v;
        __syncthreads();
    }
    int base = (t == 0) ? 0 : buf[t - 1];
    for (int i = beg; i < end; ++i) {
        rowptr[i] = base;
        cursor[i] = base;
        base += deg[i];
    }
    if (t == 1023) rowptr[N] = buf[1023];
}

__global__ void fill_k(const int* __restrict__ src, const int* __restrict__ dst,
                       int* __restrict__ cursor, int* __restrict__ srcl, int E) {
    int e = blockIdx.x * blockDim.x + threadIdx.x;
    if (e < E) {
        int p = atomicAdd(&cursor[dst[e]], 1);
        srcl[p] = src[e];
    }
}

// ---------------- mean aggregation (node-parallel, CSR) ----------------
__global__ __launch_bounds__(128) void agg_mean(const float* __restrict__ h,
        const int* __restrict__ rowptr, const int* __restrict__ srcl,
        float* __restrict__ agg) {
    int n = blockIdx.x;
    int t = threadIdx.x;
    int s0 = rowptr[n], s1 = rowptr[n + 1];
    float acc = 0.f;
    __shared__ int idx[128];
    for (int base = s0; base < s1; base += 128) {
        int cnt = min(128, s1 - base);
        if (t < cnt) idx[t] = srcl[base + t];
        __syncthreads();
        int e = 0;
        for (; e + 4 <= cnt; e += 4) {
            const float* p0 = h + (size_t)idx[e + 0] * DIM;
            const float* p1 = h + (size_t)idx[e + 1] * DIM;
            const float* p2 = h + (size_t)idx[e + 2] * DIM;
            const float* p3 = h + (size_t)idx[e + 3] * DIM;
            acc += p0[t];
            acc += p1[t];
            acc += p2[t];
            acc += p3[t];
        }
        for (; e < cnt; ++e) acc += h[(size_t)idx[e] * DIM + t];
        __syncthreads();
    }
    float d = (float)(s1 - s0);
    agg[(size_t)n * DIM + t] = acc / fmaxf(d, 1.f);
}

// ---------------- fused multi-stream GEMM ----------------
// out[m][n] = relu?( sum_s A_s[m][:] . W_s[n][:] + ba[n] (+ bb[n] if NS==3) )
// BM=32 rows/block, full N=128, K tiled by 32. 128 threads:
// tx=tid&15 -> 8 cols each, ty=tid>>4 -> 4 rows each.
template<int NS, bool RELU>
__global__ __launch_bounds__(128) void gemm_k(
        const float* __restrict__ A0, const float* __restrict__ W0,
        const float* __restrict__ A1, const float* __restrict__ W1,
        const float* __restrict__ A2, const float* __restrict__ W2,
        const float* __restrict__ ba, const float* __restrict__ bb,
        float* __restrict__ out, int M) {
    __shared__ float As[NS][32][33];     // +1 pad: broadcast reads hit distinct banks
    __shared__ float Ws[NS][32][DIM];    // transposed [k][n] for ds_read_b128
    const float* Ag[3] = {A0, A1, A2};
    const float* Wg[3] = {W0, W1, W2};
    int tid = threadIdx.x;
    int tx = tid & 15;
    int ty = tid >> 4;
    int m0 = blockIdx.x * 32;

    float acc[4][8];
#pragma unroll
    for (int i = 0; i < 4; ++i)
#pragma unroll
        for (int j = 0; j < 8; ++j) acc[i][j] = 0.f;

    for (int k0 = 0; k0 < DIM; k0 += 32) {
#pragma unroll
        for (int s = 0; s < NS; ++s) {
            // A tile: 32x32, 2 float4 per thread
#pragma unroll
            for (int r = 0; r < 2; ++r) {
                int lr = (tid >> 3) + r * 16;
                int lk = (tid & 7) * 4;
                int m = m0 + lr;
                float4 v = make_float4(0.f, 0.f, 0.f, 0.f);
                if (m < M) v = *(const float4*)(Ag[s] + (size_t)m * DIM + k0 + lk);
                As[s][lr][lk + 0] = v.x;
                As[s][lr][lk + 1] = v.y;
                As[s][lr][lk + 2] = v.z;
                As[s][lr][lk + 3] = v.w;
            }
            // W tile: 128x32, thread tid owns row n=tid; store transposed
            int n = tid;
#pragma unroll
            for (int j = 0; j < 8; ++j) {
                float4 v = *(const float4*)(Wg[s] + (size_t)n * DIM + k0 + j * 4);
                Ws[s][j * 4 + 0][n] = v.x;
                Ws[s][j * 4 + 1][n] = v.y;
                Ws[s][j * 4 + 2][n] = v.z;
                Ws[s][j * 4 + 3][n] = v.w;
            }
        }
        __syncthreads();
#pragma unroll 8
        for (int k = 0; k < 32; ++k) {
#pragma unroll
            for (int s = 0; s < NS; ++s) {
                float4 w0 = *(const float4*)&Ws[s][k][tx * 8];
                float4 w1 = *(const float4*)&Ws[s][k][tx * 8 + 4];
#pragma unroll
                for (int i = 0; i < 4; ++i) {
                    float a = As[s][ty * 4 + i][k];
                    acc[i][0] += a * w0.x; acc[i][1] += a * w0.y;
                    acc[i][2] += a * w0.z; acc[i][3] += a * w0.w;
                    acc[i][4] += a * w1.x; acc[i][5] += a * w1.y;
                    acc[i][6] += a * w1.z; acc[i][7] += a * w1.w;
                }
            }
        }
        __syncthreads();
    }

    float bias[8];
#pragma unroll
    for (int j = 0; j < 8; ++j) {
        bias[j] = ba[tx * 8 + j];
        if (NS == 3) bias[j] += bb[tx * 8 + j];
    }
#pragma unroll
    for (int i = 0; i < 4; ++i) {
        int m = m0 + ty * 4 + i;
        if (m < M) {
            float o[8];
#pragma unroll
            for (int j = 0; j < 8; ++j) {
                float v = acc[i][j] + bias[j];
                o[j] = RELU ? fmaxf(v, 0.f) : v;
            }
            float4* dp = (float4*)(out + (size_t)m * DIM + tx * 8);
            dp[0] = make_float4(o[0], o[1], o[2], o[3]);
            dp[1] = make_float4(o[4], o[5], o[6], o[7]);
        }
    }
}

extern "C" void kernel_launch(void* const* d_in, const int* in_sizes, int n_in,
                              void* d_out, int out_size, void* d_ws, size_t ws_size,
                              hipStream_t stream) {
    const float* x    = (const float*)d_in[0];
    const int*   edge = (const int*)d_in[1];
    const float* fc_w = (const float*)d_in[2];
    const float* fc_b = (const float*)d_in[3];
    const float* f_lw = (const float*)d_in[4];
    const float* f_lb = (const float*)d_in[5];
    const float* f_rw = (const float*)d_in[6];
    const float* n_lw = (const float*)d_in[7];
    const float* n_lb = (const float*)d_in[8];
    const float* n_rw = (const float*)d_in[9];
    float* out = (float*)d_out;

    const int N = NN, E = NE;
    const int* src = edge;          // edge_index[0]
    const int* dst = edge + E;      // edge_index[1]

    char* p = (char*)d_ws;
    float* h1   = (float*)p;  p += (size_t)N * DIM * sizeof(float);
    float* agg  = (float*)p;  p += (size_t)N * DIM * sizeof(float);
    int* deg    = (int*)p;    p += (size_t)N * sizeof(int);
    int* rowptr = (int*)p;    p += (size_t)(N + 1) * sizeof(int);
    int* cursor = (int*)p;    p += (size_t)N * sizeof(int);
    int* srcl   = (int*)p;

    hipMemsetAsync(deg, 0, (size_t)N * sizeof(int), stream);
    hist_k<<<(E + 255) / 256, 256, 0, stream>>>(dst, deg, E);
    scan_k<<<1, 1024, 0, stream>>>(deg, rowptr, cursor, N);
    fill_k<<<(E + 255) / 256, 256, 0, stream>>>(src, dst, cursor, srcl, E);

    // layer 1: h1 = relu(agg(x) @ f_lw^T + f_lb + x @ f_rw^T)
    agg_mean<<<N, 128, 0, stream>>>(x, rowptr, srcl, agg);
    gemm_k<2, true><<<(N + 31) / 32, 128, 0, stream>>>(
        agg, f_lw, x, f_rw, nullptr, nullptr, f_lb, nullptr, h1, N);

    // layer 2 + residual: out = relu(agg(h1) @ n_lw^T + n_lb + h1 @ n_rw^T + x @ fc_w^T + fc_b)
    agg_mean<<<N, 128, 0, stream>>>(h1, rowptr, srcl, agg);
    gemm_k<3, true><<<(N + 31) / 32, 128, 0, stream>>>(
        agg, n_lw, h1, n_rw, x, fc_w, n_lb, fc_b, out, N);
}

// Round 2
// 270.743 us; speedup vs baseline: 1.1031x; 1.1031x over previous
//
#include <hip/hip_runtime.h>

#define NN 10000
#define NE 640000
#define DIM 128

// ---------------- CSR build ----------------
__global__ void hist_k(const int* __restrict__ dst, int* __restrict__ deg, int E) {
    int e = blockIdx.x * blockDim.x + threadIdx.x;
    if (e < E) atomicAdd(&deg[dst[e]], 1);
}

__global__ __launch_bounds__(1024) void scan_k(const int* __restrict__ deg,
        int* __restrict__ rowptr, int* __restrict__ cursor, int N) {
    __shared__ int buf[1024];
    int t = threadIdx.x;
    int chunk = (N + 1023) >> 10;
    int beg = t * chunk;
    int end = min(beg + chunk, N);
    int sum = 0;
    for (int i = beg; i < end; ++i) sum += deg[i];
    buf[t] = sum;
    __syncthreads();
    for (int off = 1; off < 1024; off <<= 1) {
        int v = (t >= off) ? buf[t - off] : 0;
        __syncthreads();
        buf[t] += v;
        __syncthreads();
    }
    int base = (t == 0) ? 0 : buf[t - 1];
    for (int i = beg; i < end; ++i) {
        rowptr[i] = base;
        cursor[i] = base;
        base += deg[i];
    }
    if (t == 1023) rowptr[N] = buf[1023];
}

__global__ void fill_k(const int* __restrict__ src, const int* __restrict__ dst,
                       int* __restrict__ cursor, int* __restrict__ srcl, int E) {
    int e = blockIdx.x * blockDim.x + threadIdx.x;
    if (e < E) {
        int p = atomicAdd(&cursor[dst[e]], 1);
        srcl[p] = src[e];
    }
}

// ---------------- wide GEMM: out[plane][m][:] = A[m][:] @ W_plane^T ----------------
// 256 threads, BM=32 rows, BN=128 cols (one weight plane per blockIdx.y).
// Each thread: 2 rows x 8 cols. K tiled by 32; W staged transposed [k][n] in LDS.
__global__ __launch_bounds__(256) void gemm_k(
        const float* __restrict__ A,
        const float* __restrict__ W0, const float* __restrict__ W1,
        const float* __restrict__ W2,
        float* __restrict__ out, int M) {
    const float* W = (blockIdx.y == 0) ? W0 : ((blockIdx.y == 1) ? W1 : W2);
    float* o = out + (size_t)blockIdx.y * M * DIM;

    __shared__ float Ws[32][DIM];   // [k][n] transposed
    __shared__ float As[32][33];    // +1 pad

    int tid = threadIdx.x;
    int tx = tid & 15;        // col group: 8 cols
    int ty = tid >> 4;        // row group: 2 rows
    int m0 = blockIdx.x * 32;

    float acc[2][8];
#pragma unroll
    for (int i = 0; i < 2; ++i)
#pragma unroll
        for (int j = 0; j < 8; ++j) acc[i][j] = 0.f;

    for (int k0 = 0; k0 < DIM; k0 += 32) {
        // stage W chunk: thread -> row n = tid>>1, half kh = (tid&1)*16
        {
            int n = tid >> 1;
            int kh = (tid & 1) * 16;
#pragma unroll
            for (int j = 0; j < 4; ++j) {
                float4 v = *(const float4*)(W + (size_t)n * DIM + k0 + kh + j * 4);
                Ws[kh + j * 4 + 0][n] = v.x;
                Ws[kh + j * 4 + 1][n] = v.y;
                Ws[kh + j * 4 + 2][n] = v.z;
                Ws[kh + j * 4 + 3][n] = v.w;
            }
        }
        // stage A tile: 32x32, one float4 per thread
        {
            int lr = tid >> 3;
            int lk = (tid & 7) * 4;
            int m = m0 + lr;
            float4 v = make_float4(0.f, 0.f, 0.f, 0.f);
            if (m < M) v = *(const float4*)(A + (size_t)m * DIM + k0 + lk);
            As[lr][lk + 0] = v.x;
            As[lr][lk + 1] = v.y;
            As[lr][lk + 2] = v.z;
            As[lr][lk + 3] = v.w;
        }
        __syncthreads();
#pragma unroll
        for (int k = 0; k < 32; ++k) {
            float4 w0 = *(const float4*)&Ws[k][tx * 8];
            float4 w1 = *(const float4*)&Ws[k][tx * 8 + 4];
            float a0 = As[ty * 2 + 0][k];
            float a1 = As[ty * 2 + 1][k];
            acc[0][0] += a0 * w0.x; acc[0][1] += a0 * w0.y;
            acc[0][2] += a0 * w0.z; acc[0][3] += a0 * w0.w;
            acc[0][4] += a0 * w1.x; acc[0][5] += a0 * w1.y;
            acc[0][6] += a0 * w1.z; acc[0][7] += a0 * w1.w;
            acc[1][0] += a1 * w0.x; acc[1][1] += a1 * w0.y;
            acc[1][2] += a1 * w0.z; acc[1][3] += a1 * w0.w;
            acc[1][4] += a1 * w1.x; acc[1][5] += a1 * w1.y;
            acc[1][6] += a1 * w1.z; acc[1][7] += a1 * w1.w;
        }
        __syncthreads();
    }

#pragma unroll
    for (int i = 0; i < 2; ++i) {
        int m = m0 + ty * 2 + i;
        if (m < M) {
            float4* dp = (float4*)(o + (size_t)m * DIM + tx * 8);
            dp[0] = make_float4(acc[i][0], acc[i][1], acc[i][2], acc[i][3]);
            dp[1] = make_float4(acc[i][4], acc[i][5], acc[i][6], acc[i][7]);
        }
    }
}

// ---------------- fused aggregation + epilogue ----------------
// One block per node, 256 threads = 8 neighbor-groups x 32 float4 dim-lanes.
// out[n] = relu( mean_{s in nbr(n)} xl[s] + xr[n] + b0 (+ xc[n] + b1) )
template<bool HAS_C>
__global__ __launch_bounds__(256) void agg_k(
        const float* __restrict__ xl, const float* __restrict__ xr,
        const float* __restrict__ xc,
        const float* __restrict__ b0, const float* __restrict__ b1,
        const int* __restrict__ rowptr, const int* __restrict__ srcl,
        float* __restrict__ out) {
    int n = blockIdx.x;
    int d4 = threadIdx.x & 31;   // float4 index within row
    int g  = threadIdx.x >> 5;   // neighbor group 0..7
    int s0 = rowptr[n], s1 = rowptr[n + 1];

    float4 acc = make_float4(0.f, 0.f, 0.f, 0.f);
    int e = s0 + g;
    for (; e + 8 < s1; e += 16) {
        int i0 = srcl[e];
        int i1 = srcl[e + 8];
        float4 v0 = *(const float4*)(xl + (size_t)i0 * DIM + d4 * 4);
        float4 v1 = *(const float4*)(xl + (size_t)i1 * DIM + d4 * 4);
        acc.x += v0.x + v1.x; acc.y += v0.y + v1.y;
        acc.z += v0.z + v1.z; acc.w += v0.w + v1.w;
    }
    if (e < s1) {
        int i0 = srcl[e];
        float4 v0 = *(const float4*)(xl + (size_t)i0 * DIM + d4 * 4);
        acc.x += v0.x; acc.y += v0.y; acc.z += v0.z; acc.w += v0.w;
    }

    __shared__ float4 red[8][32];
    red[g][d4] = acc;
    __syncthreads();
    if (g == 0) {
        float4 s = red[0][d4];
#pragma unroll
        for (int i = 1; i < 8; ++i) {
            float4 t = red[i][d4];
            s.x += t.x; s.y += t.y; s.z += t.z; s.w += t.w;
        }
        float inv = 1.f / fmaxf((float)(s1 - s0), 1.f);
        float4 r = *(const float4*)(xr + (size_t)n * DIM + d4 * 4);
        float4 bv = *(const float4*)(b0 + d4 * 4);
        float4 ov;
        ov.x = s.x * inv + r.x + bv.x;
        ov.y = s.y * inv + r.y + bv.y;
        ov.z = s.z * inv + r.z + bv.z;
        ov.w = s.w * inv + r.w + bv.w;
        if (HAS_C) {
            float4 c = *(const float4*)(xc + (size_t)n * DIM + d4 * 4);
            float4 b2 = *(const float4*)(b1 + d4 * 4);
            ov.x += c.x + b2.x; ov.y += c.y + b2.y;
            ov.z += c.z + b2.z; ov.w += c.w + b2.w;
        }
        ov.x = fmaxf(ov.x, 0.f); ov.y = fmaxf(ov.y, 0.f);
        ov.z = fmaxf(ov.z, 0.f); ov.w = fmaxf(ov.w, 0.f);
        *(float4*)(out + (size_t)n * DIM + d4 * 4) = ov;
    }
}

extern "C" void kernel_launch(void* const* d_in, const int* in_sizes, int n_in,
                              void* d_out, int out_size, void* d_ws, size_t ws_size,
                              hipStream_t stream) {
    const float* x    = (const float*)d_in[0];
    const int*   edge = (const int*)d_in[1];
    const float* fc_w = (const float*)d_in[2];
    const float* fc_b = (const float*)d_in[3];
    const float* f_lw = (const float*)d_in[4];
    const float* f_lb = (const float*)d_in[5];
    const float* f_rw = (const float*)d_in[6];
    const float* n_lw = (const float*)d_in[7];
    const float* n_lb = (const float*)d_in[8];
    const float* n_rw = (const float*)d_in[9];
    float* out = (float*)d_out;

    const int N = NN, E = NE;
    const int* src = edge;       // edge_index[0]
    const int* dst = edge + E;   // edge_index[1]

    char* p = (char*)d_ws;
    float* T    = (float*)p;  p += (size_t)3 * N * DIM * sizeof(float); // planes xl|xr|xc
    float* h1   = (float*)p;  p += (size_t)N * DIM * sizeof(float);
    int* deg    = (int*)p;    p += (size_t)N * sizeof(int);
    int* rowptr = (int*)p;    p += (size_t)(N + 1) * sizeof(int);
    int* cursor = (int*)p;    p += (size_t)N * sizeof(int);
    int* srcl   = (int*)p;

    float* xl = T;
    float* xr = T + (size_t)N * DIM;
    float* xc = T + (size_t)2 * N * DIM;
    // GEMM2 output planes alias xl/xr (consumed by then)
    float* ul = xl;
    float* ur = xr;

    // CSR build
    hipMemsetAsync(deg, 0, (size_t)N * sizeof(int), stream);
    hist_k<<<(E + 255) / 256, 256, 0, stream>>>(dst, deg, E);
    scan_k<<<1, 1024, 0, stream>>>(deg, rowptr, cursor, N);
    fill_k<<<(E + 255) / 256, 256, 0, stream>>>(src, dst, cursor, srcl, E);

    // GEMM1: T = x @ [f_lw | f_rw | fc_w]^T   (linearity: agg(x)@W^T == agg(x@W^T))
    {
        dim3 grid((N + 31) / 32, 3);
        gemm_k<<<grid, 256, 0, stream>>>(x, f_lw, f_rw, fc_w, T, N);
    }
    // h1 = relu(mean_agg(xl) + xr + f_lb)
    agg_k<false><<<N, 256, 0, stream>>>(xl, xr, nullptr, f_lb, nullptr,
                                        rowptr, srcl, h1);
    // GEMM2: [ul|ur] = h1 @ [n_lw | n_rw]^T
    {
        dim3 grid((N + 31) / 32, 2);
        gemm_k<<<grid, 256, 0, stream>>>(h1, n_lw, n_rw, n_rw, T, N);
    }
    // out = relu(mean_agg(ul) + ur + n_lb + xc + fc_b)
    agg_k<true><<<N, 256, 0, stream>>>(ul, ur, xc, n_lb, fc_b,
                                       rowptr, srcl, out);
}

// Round 3
// 241.591 us; speedup vs baseline: 1.2362x; 1.1207x over previous
//
#include <hip/hip_runtime.h>

#define NN 10000
#define NE 640000
#define DIM 128
#define MT 157   // ceil(NN/64) row-tiles per weight plane

__device__ __forceinline__ unsigned short f2bf(float f) {
    unsigned u = __float_as_uint(f);
    u += 0x7FFFu + ((u >> 16) & 1u);          // round-to-nearest-even
    return (unsigned short)(u >> 16);
}
__device__ __forceinline__ float bf2f(unsigned short h) {
    return __uint_as_float(((unsigned)h) << 16);
}

// ---------------- CSR scan ----------------
__global__ __launch_bounds__(1024) void scan_k(const int* __restrict__ deg,
        int* __restrict__ rowptr, int* __restrict__ cursor, int N) {
    __shared__ int buf[1024];
    int t = threadIdx.x;
    int chunk = (N + 1023) >> 10;
    int beg = t * chunk;
    int end = min(beg + chunk, N);
    int sum = 0;
    for (int i = beg; i < end; ++i) sum += deg[i];
    buf[t] = sum;
    __syncthreads();
    for (int off = 1; off < 1024; off <<= 1) {
        int v = (t >= off) ? buf[t - off] : 0;
        __syncthreads();
        buf[t] += v;
        __syncthreads();
    }
    int base = (t == 0) ? 0 : buf[t - 1];
    for (int i = beg; i < end; ++i) {
        rowptr[i] = base;
        cursor[i] = base;
        base += deg[i];
    }
    if (t == 1023) rowptr[N] = buf[1023];
}

__global__ __launch_bounds__(256) void fill_k(const int* __restrict__ src,
        const int* __restrict__ dst, int* __restrict__ cursor,
        int* __restrict__ srcl, int E) {
    int e4 = (blockIdx.x * 256 + threadIdx.x) * 4;
    if (e4 + 3 < E) {
        int4 s = *(const int4*)(src + e4);
        int4 d = *(const int4*)(dst + e4);
        int p;
        p = atomicAdd(&cursor[d.x], 1); srcl[p] = s.x;
        p = atomicAdd(&cursor[d.y], 1); srcl[p] = s.y;
        p = atomicAdd(&cursor[d.z], 1); srcl[p] = s.z;
        p = atomicAdd(&cursor[d.w], 1); srcl[p] = s.w;
    }
}

// ---------------- fused GEMM (+optional histogram blocks) ----------------
// gemm blocks: BM=64 rows x BN=128 cols, 256 threads, K tiled by 32.
// plane 0 writes bf16 (gather plane), planes 1/2 write fp32.
// blocks >= gemmBlocks run the degree histogram (independent work, overlapped).
__global__ __launch_bounds__(256) void gemm_hist_k(
        const float* __restrict__ A,
        const float* __restrict__ W0, const float* __restrict__ W1,
        const float* __restrict__ W2,
        unsigned short* __restrict__ obf,
        float* __restrict__ o1, float* __restrict__ o2,
        int M, int gemmBlocks,
        const int* __restrict__ dst, int* __restrict__ deg, int E) {
    if ((int)blockIdx.x >= gemmBlocks) {
        int hb = (int)blockIdx.x - gemmBlocks;
        int e4 = (hb * 256 + (int)threadIdx.x) * 4;
        if (e4 + 3 < E) {
            int4 d = *(const int4*)(dst + e4);
            atomicAdd(&deg[d.x], 1);
            atomicAdd(&deg[d.y], 1);
            atomicAdd(&deg[d.z], 1);
            atomicAdd(&deg[d.w], 1);
        }
        return;
    }
    __shared__ float Ws[32][128];   // [k][n] transposed weight tile
    __shared__ float As[32][68];    // [k][m] transposed A tile (stride 68: 16B-aligned rows)

    int plane = (int)blockIdx.x / MT;
    int mt    = (int)blockIdx.x % MT;
    const float* W = (plane == 0) ? W0 : ((plane == 1) ? W1 : W2);

    int tid = threadIdx.x;
    int tx = tid & 15;     // 8 cols: 4*tx..+3 and 64+4*tx..+3
    int ty = tid >> 4;     // 4 rows: 4*ty..+3
    int m0 = mt * 64;

    float acc[4][8];
#pragma unroll
    for (int i = 0; i < 4; ++i)
#pragma unroll
        for (int j = 0; j < 8; ++j) acc[i][j] = 0.f;

    for (int k0 = 0; k0 < DIM; k0 += 32) {
        // stage W: thread -> row wn=tid>>1, half wk=(tid&1)*16; 2-way bank alias on writes (free)
        {
            int wn = tid >> 1;
            int wk = (tid & 1) * 16;
#pragma unroll
            for (int j = 0; j < 4; ++j) {
                float4 v = *(const float4*)(W + (size_t)wn * DIM + k0 + wk + j * 4);
                Ws[wk + j * 4 + 0][wn] = v.x;
                Ws[wk + j * 4 + 1][wn] = v.y;
                Ws[wk + j * 4 + 2][wn] = v.z;
                Ws[wk + j * 4 + 3][wn] = v.w;
            }
        }
        // stage A transposed: thread -> row lr=tid>>2, k-span lk=(tid&3)*8
        {
            int lr = tid >> 2;
            int lk = (tid & 3) * 8;
            int m = m0 + lr;
            float4 va = make_float4(0.f, 0.f, 0.f, 0.f);
            float4 vb = make_float4(0.f, 0.f, 0.f, 0.f);
            if (m < M) {
                va = *(const float4*)(A + (size_t)m * DIM + k0 + lk);
                vb = *(const float4*)(A + (size_t)m * DIM + k0 + lk + 4);
            }
            As[lk + 0][lr] = va.x; As[lk + 1][lr] = va.y;
            As[lk + 2][lr] = va.z; As[lk + 3][lr] = va.w;
            As[lk + 4][lr] = vb.x; As[lk + 5][lr] = vb.y;
            As[lk + 6][lr] = vb.z; As[lk + 7][lr] = vb.w;
        }
        __syncthreads();
#pragma unroll
        for (int k = 0; k < 32; ++k) {
            float4 a  = *(const float4*)&As[k][ty * 4];
            float4 w0 = *(const float4*)&Ws[k][tx * 4];
            float4 w1 = *(const float4*)&Ws[k][64 + tx * 4];
            acc[0][0] += a.x * w0.x; acc[0][1] += a.x * w0.y;
            acc[0][2] += a.x * w0.z; acc[0][3] += a.x * w0.w;
            acc[0][4] += a.x * w1.x; acc[0][5] += a.x * w1.y;
            acc[0][6] += a.x * w1.z; acc[0][7] += a.x * w1.w;
            acc[1][0] += a.y * w0.x; acc[1][1] += a.y * w0.y;
            acc[1][2] += a.y * w0.z; acc[1][3] += a.y * w0.w;
            acc[1][4] += a.y * w1.x; acc[1][5] += a.y * w1.y;
            acc[1][6] += a.y * w1.z; acc[1][7] += a.y * w1.w;
            acc[2][0] += a.z * w0.x; acc[2][1] += a.z * w0.y;
            acc[2][2] += a.z * w0.z; acc[2][3] += a.z * w0.w;
            acc[2][4] += a.z * w1.x; acc[2][5] += a.z * w1.y;
            acc[2][6] += a.z * w1.z; acc[2][7] += a.z * w1.w;
            acc[3][0] += a.w * w0.x; acc[3][1] += a.w * w0.y;
            acc[3][2] += a.w * w0.z; acc[3][3] += a.w * w0.w;
            acc[3][4] += a.w * w1.x; acc[3][5] += a.w * w1.y;
            acc[3][6] += a.w * w1.z; acc[3][7] += a.w * w1.w;
        }
        __syncthreads();
    }

#pragma unroll
    for (int i = 0; i < 4; ++i) {
        int m = m0 + ty * 4 + i;
        if (m >= M) continue;
        if (plane == 0) {
            ushort4 p0, p1;
            p0.x = f2bf(acc[i][0]); p0.y = f2bf(acc[i][1]);
            p0.z = f2bf(acc[i][2]); p0.w = f2bf(acc[i][3]);
            p1.x = f2bf(acc[i][4]); p1.y = f2bf(acc[i][5]);
            p1.z = f2bf(acc[i][6]); p1.w = f2bf(acc[i][7]);
            *(ushort4*)(obf + (size_t)m * DIM + tx * 4)      = p0;
            *(ushort4*)(obf + (size_t)m * DIM + 64 + tx * 4) = p1;
        } else {
            float* o = (plane == 1) ? o1 : o2;
            *(float4*)(o + (size_t)m * DIM + tx * 4) =
                make_float4(acc[i][0], acc[i][1], acc[i][2], acc[i][3]);
            *(float4*)(o + (size_t)m * DIM + 64 + tx * 4) =
                make_float4(acc[i][4], acc[i][5], acc[i][6], acc[i][7]);
        }
    }
}

// ---------------- fused mean-aggregation + epilogue (bf16 gather plane) ----------------
// out[n] = relu( mean_{s in nbr(n)} xlb[s] + xr[n] + b0 (+ xc[n] + b1) )
template<bool HAS_C>
__global__ __launch_bounds__(256) void agg_k(
        const unsigned short* __restrict__ xlb,
        const float* __restrict__ xr, const float* __restrict__ xc,
        const float* __restrict__ b0, const float* __restrict__ b1,
        const int* __restrict__ rowptr, const int* __restrict__ srcl,
        float* __restrict__ out) {
    int n = blockIdx.x;
    int d4 = threadIdx.x & 31;   // ushort4 index within row
    int g  = threadIdx.x >> 5;   // neighbor group 0..7
    int s0 = rowptr[n], s1 = rowptr[n + 1];

    float4 acc = make_float4(0.f, 0.f, 0.f, 0.f);
    int e = s0 + g;
    for (; e + 8 < s1; e += 16) {
        int i0 = srcl[e];
        int i1 = srcl[e + 8];
        ushort4 u0 = *(const ushort4*)(xlb + (size_t)i0 * DIM + d4 * 4);
        ushort4 u1 = *(const ushort4*)(xlb + (size_t)i1 * DIM + d4 * 4);
        acc.x += bf2f(u0.x) + bf2f(u1.x);
        acc.y += bf2f(u0.y) + bf2f(u1.y);
        acc.z += bf2f(u0.z) + bf2f(u1.z);
        acc.w += bf2f(u0.w) + bf2f(u1.w);
    }
    if (e < s1) {
        int i0 = srcl[e];
        ushort4 u0 = *(const ushort4*)(xlb + (size_t)i0 * DIM + d4 * 4);
        acc.x += bf2f(u0.x); acc.y += bf2f(u0.y);
        acc.z += bf2f(u0.z); acc.w += bf2f(u0.w);
    }

    __shared__ float4 red[8][32];
    red[g][d4] = acc;
    __syncthreads();
    if (g == 0) {
        float4 s = red[0][d4];
#pragma unroll
        for (int i = 1; i < 8; ++i) {
            float4 t = red[i][d4];
            s.x += t.x; s.y += t.y; s.z += t.z; s.w += t.w;
        }
        float inv = 1.f / fmaxf((float)(s1 - s0), 1.f);
        float4 r  = *(const float4*)(xr + (size_t)n * DIM + d4 * 4);
        float4 bv = *(const float4*)(b0 + d4 * 4);
        float4 ov;
        ov.x = s.x * inv + r.x + bv.x;
        ov.y = s.y * inv + r.y + bv.y;
        ov.z = s.z * inv + r.z + bv.z;
        ov.w = s.w * inv + r.w + bv.w;
        if (HAS_C) {
            float4 c  = *(const float4*)(xc + (size_t)n * DIM + d4 * 4);
            float4 b2 = *(const float4*)(b1 + d4 * 4);
            ov.x += c.x + b2.x; ov.y += c.y + b2.y;
            ov.z += c.z + b2.z; ov.w += c.w + b2.w;
        }
        ov.x = fmaxf(ov.x, 0.f); ov.y = fmaxf(ov.y, 0.f);
        ov.z = fmaxf(ov.z, 0.f); ov.w = fmaxf(ov.w, 0.f);
        *(float4*)(out + (size_t)n * DIM + d4 * 4) = ov;
    }
}

extern "C" void kernel_launch(void* const* d_in, const int* in_sizes, int n_in,
                              void* d_out, int out_size, void* d_ws, size_t ws_size,
                              hipStream_t stream) {
    const float* x    = (const float*)d_in[0];
    const int*   edge = (const int*)d_in[1];
    const float* fc_w = (const float*)d_in[2];
    const float* fc_b = (const float*)d_in[3];
    const float* f_lw = (const float*)d_in[4];
    const float* f_lb = (const float*)d_in[5];
    const float* f_rw = (const float*)d_in[6];
    const float* n_lw = (const float*)d_in[7];
    const float* n_lb = (const float*)d_in[8];
    const float* n_rw = (const float*)d_in[9];
    float* out = (float*)d_out;

    const int N = NN, E = NE;
    const int* src = edge;       // edge_index[0]
    const int* dst = edge + E;   // edge_index[1]

    char* p = (char*)d_ws;
    float* xr = (float*)p;           p += (size_t)N * DIM * sizeof(float);
    float* xc = (float*)p;           p += (size_t)N * DIM * sizeof(float);
    float* h1 = (float*)p;           p += (size_t)N * DIM * sizeof(float);
    unsigned short* xlb = (unsigned short*)p;  p += (size_t)N * DIM * sizeof(unsigned short);
    int* deg    = (int*)p;           p += (size_t)N * sizeof(int);
    int* rowptr = (int*)p;           p += (size_t)(N + 4) * sizeof(int);
    int* cursor = (int*)p;           p += (size_t)N * sizeof(int);
    int* srcl   = (int*)p;

    const int G_GEMM1 = 3 * MT;          // 471
    const int G_HIST  = E / 1024;        // 625 (4 edges/thread)
    const int G_GEMM2 = 2 * MT;          // 314

    hipMemsetAsync(deg, 0, (size_t)N * sizeof(int), stream);

    // GEMM1 (x @ [f_lw|f_rw|fc_w]^T) + degree histogram in one dispatch
    gemm_hist_k<<<G_GEMM1 + G_HIST, 256, 0, stream>>>(
        x, f_lw, f_rw, fc_w, xlb, xr, xc, N, G_GEMM1, dst, deg, E);
    scan_k<<<1, 1024, 0, stream>>>(deg, rowptr, cursor, N);
    fill_k<<<(E / 1024), 256, 0, stream>>>(src, dst, cursor, srcl, E);

    // h1 = relu(mean_agg(xlb) + xr + f_lb)
    agg_k<false><<<N, 256, 0, stream>>>(xlb, xr, nullptr, f_lb, nullptr,
                                        rowptr, srcl, h1);
    // GEMM2: h1 @ [n_lw|n_rw]^T  (plane0 -> bf16 gather plane, plane1 -> fp32)
    gemm_hist_k<<<G_GEMM2, 256, 0, stream>>>(
        h1, n_lw, n_rw, n_rw, xlb, xr, nullptr, N, G_GEMM2, dst, deg, E);
    // out = relu(mean_agg(xlb) + xr + n_lb + xc + fc_b)
    agg_k<true><<<N, 256, 0, stream>>>(xlb, xr, xc, n_lb, fc_b,
                                       rowptr, srcl, out);
}